// Round 1
// baseline (77.679 us; speedup 1.0000x reference)
//
#include <hip/hip_runtime.h>
#include <math.h>

#define EPS 1e-9f

__device__ __forceinline__ int tri_off(int I) { return I * (193 - I) / 2; }  // 96 tiles

// ---------------------------------------------------------------------------
// Main pass: symmetric tile-pair kernel, register-rotation scatter.
// Pair math is IDENTICAL to the verified R11 kernel. The only change vs the
// 77 µs version is the output path: instead of ~190 cross-XCD atomicAdd
// line-visits per output cache line (coherence ping-pong ~= 35 us), each wave
// stores its two 64-body partial vectors to private written-exactly-once
// workspace slots ws[(T*96+P)*64+lane], and reduce_ws sums the 96 partials
// per tile. No global atomics anywhere; no out[] zeroing needed.
// ---------------------------------------------------------------------------
__global__ __launch_bounds__(256)
void collide_ws(const float2* __restrict__ cpos,
                const float*  __restrict__ crad,
                const float2* __restrict__ apos,
                const float2* __restrict__ ahalf,
                float2* __restrict__ ws,
                int Nc) {
    const int lane = threadIdx.x & 63;
    const int w    = threadIdx.x >> 6;
    const int t    = blockIdx.x * 4 + w;          // tile-pair id 0..4655 (uniform)

    // triangular decode t -> (I, J), I <= J  (37249 - 8t exact in f32)
    int I = (int)((193.0f - sqrtf((float)(37249 - 8 * t))) * 0.5f);
    while (tri_off(I + 1) <= t) ++I;
    while (tri_off(I) > t) --I;
    const int J = I + (t - tri_off(I));

    const int tileC  = Nc >> 6;                   // 64 circle tiles
    const bool bodyC = I < tileC;                 // uniform
    const bool partC = J < tileC;                 // uniform (I<=J: partC => bodyC)

    __shared__ float4 Jd[4][128];

    {   // stage J tile (doubled) straight from inputs; circle radius pre-halved
        const int j = (J << 6) + lane;
        float4 q;
        if (partC) {
            const float2 c = cpos[j];
            q = make_float4(c.x, c.y, 0.5f * crad[j], 0.0f);
        } else {
            const float2 a = apos[j - Nc];
            const float2 h = ahalf[j - Nc];
            q = make_float4(a.x, a.y, h.x, h.y);
        }
        Jd[w][lane]      = q;
        Jd[w][lane + 64] = q;
    }
    __syncthreads();

    const int i = (I << 6) + lane;
    float4 me;
    if (bodyC) {
        const float2 c = cpos[i];
        me = make_float4(c.x, c.y, 0.5f * crad[i], 0.0f);
    } else {
        const float2 a = apos[i - Nc];
        const float2 h = ahalf[i - Nc];
        me = make_float4(a.x, a.y, h.x, h.y);
    }

    float ax = 0.0f, ay = 0.0f;
    const int src = (lane + 1) & 63;              // rotation source lane

    if (I != J) {
        float gx = 0.0f, gy = 0.0f;               // rotating J-side accumulator
        if (partC) {                              // CC (both circle tiles)
            const float px = me.x, py = me.y, rih = me.z;
            #pragma unroll 4
            for (int m = 0; m < 64; ++m) {
                const float4 q = Jd[w][lane + m];
                const float dx = q.x - px, dy = q.y - py;        // q - p
                const float d2 = fmaf(dx, dx, dy * dy);
                const float r  = __builtin_amdgcn_rsqf(d2);
                const float s  = fmaxf(fmaf(rih + q.z, r, -0.5f), 0.0f);
                const float fx = s * dx, fy = s * dy;            // force on J body
                ax -= fx; ay -= fy;                              // equal & opposite on I
                gx += fx; gy += fy;
                gx = __shfl(gx, src, 64);                        // rotate accumulator
                gy = __shfl(gy, src, 64);
            }
        } else if (bodyC) {                       // CB: I circle tile, J box tile
            const float px = me.x, py = me.y, rih = me.z;
            #pragma unroll 4
            for (int m = 0; m < 64; ++m) {
                const float4 q = Jd[w][lane + m];
                const float rx = q.x - px, ry = q.y - py;        // box - circle
                const float cx = fminf(fmaxf(rx, -q.z), q.z);
                const float cy = fminf(fmaxf(ry, -q.w), q.w);
                const float dx = rx - cx, dy = ry - cy;          // = -(ref diff)
                const float d2 = fmaf(dx, dx, dy * dy);
                const float r  = __builtin_amdgcn_rsqf(d2);
                float s = fmaxf(fmaf(rih, r, -0.5f), 0.0f);
                s = (d2 > EPS) ? s : 0.0f;                       // center-inside-box guard
                const float fx = s * dx, fy = s * dy;            // force on box
                ax -= fx; ay -= fy;                              // push on circle
                gx += fx; gy += fy;
                gx = __shfl(gx, src, 64);
                gy = __shfl(gy, src, 64);
            }
        } else {                                  // BB (both box tiles)
            const float bx = me.x, by = me.y, hx = me.z, hy = me.w;
            #pragma unroll 4
            for (int m = 0; m < 64; ++m) {
                const float4 q = Jd[w][lane + m];
                const float dqx = q.x - bx, dqy = q.y - by;      // q - me
                const float ovx = (hx + q.z) - fabsf(dqx);
                const float ovy = (hy + q.w) - fabsf(dqy);
                const bool hit = fminf(ovx, ovy) > 0.0f;
                const bool ux  = ovx <= ovy;
                const float fx = (hit && ux)  ? copysignf(0.5f * ovx, dqx) : 0.0f;
                const float fy = (hit && !ux) ? copysignf(0.5f * ovy, dqy) : 0.0f;
                ax -= fx; ay -= fy;
                gx += fx; gy += fy;
                gx = __shfl(gx, src, 64);
                gy = __shfl(gy, src, 64);
            }
        }
        // J-side partial: slot [J][I][lane], written exactly once
        ws[(J * 96 + I) * 64 + lane] = make_float2(gx, gy);
    } else {
        // diagonal: gather k=1..63; fold base position here (unique per body)
        if (bodyC) {                              // CC diag
            const float px = me.x, py = me.y, rih = me.z;
            #pragma unroll 7
            for (int k = 1; k < 64; ++k) {
                const float4 q = Jd[w][lane + k];
                const float dx = px - q.x, dy = py - q.y;        // p - q (I side)
                const float d2 = fmaf(dx, dx, dy * dy);
                const float r  = __builtin_amdgcn_rsqf(d2);
                const float s  = fmaxf(fmaf(rih + q.z, r, -0.5f), 0.0f);
                ax = fmaf(s, dx, ax); ay = fmaf(s, dy, ay);
            }
        } else {                                  // BB diag
            const float bx = me.x, by = me.y, hx = me.z, hy = me.w;
            #pragma unroll 7
            for (int k = 1; k < 64; ++k) {
                const float4 q = Jd[w][lane + k];
                const float dax = bx - q.x, day = by - q.y;
                const float ovx = (hx + q.z) - fabsf(dax);
                const float ovy = (hy + q.w) - fabsf(day);
                const bool hit = fminf(ovx, ovy) > 0.0f;
                const bool ux  = ovx <= ovy;
                ax += (hit && ux)  ? copysignf(0.5f * ovx, dax) : 0.0f;
                ay += (hit && !ux) ? copysignf(0.5f * ovy, day) : 0.0f;
            }
        }
        ax += me.x; ay += me.y;                   // base position
    }

    // I-side partial (diag: the [I][I] slot): written exactly once
    ws[(I * 96 + J) * 64 + lane] = make_float2(ax, ay);
}

// ---------------------------------------------------------------------------
// Reduce: out[T*64+l] = sum_P ws[T][P][l]. 96 blocks x 1 wave; per-P load is
// 64 consecutive float2 = 512 B coalesced. Reads 4.7 MB total, writes out
// exactly once (no memset needed). Deterministic summation order.
// ---------------------------------------------------------------------------
__global__ __launch_bounds__(64)
void reduce_ws(const float2* __restrict__ ws, float2* __restrict__ out) {
    const int T = blockIdx.x;                     // 0..95
    const int l = threadIdx.x;                    // 0..63
    const float2* row = ws + (size_t)(T * 96) * 64 + l;
    float sx = 0.0f, sy = 0.0f;
    #pragma unroll 8
    for (int P = 0; P < 96; ++P) {
        const float2 v = row[(size_t)P * 64];
        sx += v.x; sy += v.y;
    }
    out[(T << 6) + l] = make_float2(sx, sy);
}

// ---------------------------------------------------------------------------
// Fallback: original verified atomic-scatter kernel (used only if d_ws is
// unexpectedly too small for the 4.72 MB partial buffer).
// ---------------------------------------------------------------------------
__global__ __launch_bounds__(256)
void collide_atomic(const float2* __restrict__ cpos,
                    const float*  __restrict__ crad,
                    const float2* __restrict__ apos,
                    const float2* __restrict__ ahalf,
                    float* __restrict__ out,
                    int Nc) {
    const int lane = threadIdx.x & 63;
    const int w    = threadIdx.x >> 6;
    const int t    = blockIdx.x * 4 + w;

    int I = (int)((193.0f - sqrtf((float)(37249 - 8 * t))) * 0.5f);
    while (tri_off(I + 1) <= t) ++I;
    while (tri_off(I) > t) --I;
    const int J = I + (t - tri_off(I));

    const int tileC  = Nc >> 6;
    const bool bodyC = I < tileC;
    const bool partC = J < tileC;

    __shared__ float4 Jd[4][128];

    {
        const int j = (J << 6) + lane;
        float4 q;
        if (partC) {
            const float2 c = cpos[j];
            q = make_float4(c.x, c.y, 0.5f * crad[j], 0.0f);
        } else {
            const float2 a = apos[j - Nc];
            const float2 h = ahalf[j - Nc];
            q = make_float4(a.x, a.y, h.x, h.y);
        }
        Jd[w][lane]      = q;
        Jd[w][lane + 64] = q;
    }
    __syncthreads();

    const int i = (I << 6) + lane;
    float4 me;
    if (bodyC) {
        const float2 c = cpos[i];
        me = make_float4(c.x, c.y, 0.5f * crad[i], 0.0f);
    } else {
        const float2 a = apos[i - Nc];
        const float2 h = ahalf[i - Nc];
        me = make_float4(a.x, a.y, h.x, h.y);
    }

    float ax = 0.0f, ay = 0.0f;
    const int src = (lane + 1) & 63;

    if (I != J) {
        float gx = 0.0f, gy = 0.0f;
        if (partC) {
            const float px = me.x, py = me.y, rih = me.z;
            #pragma unroll 4
            for (int m = 0; m < 64; ++m) {
                const float4 q = Jd[w][lane + m];
                const float dx = q.x - px, dy = q.y - py;
                const float d2 = fmaf(dx, dx, dy * dy);
                const float r  = __builtin_amdgcn_rsqf(d2);
                const float s  = fmaxf(fmaf(rih + q.z, r, -0.5f), 0.0f);
                const float fx = s * dx, fy = s * dy;
                ax -= fx; ay -= fy;
                gx += fx; gy += fy;
                gx = __shfl(gx, src, 64);
                gy = __shfl(gy, src, 64);
            }
        } else if (bodyC) {
            const float px = me.x, py = me.y, rih = me.z;
            #pragma unroll 4
            for (int m = 0; m < 64; ++m) {
                const float4 q = Jd[w][lane + m];
                const float rx = q.x - px, ry = q.y - py;
                const float cx = fminf(fmaxf(rx, -q.z), q.z);
                const float cy = fminf(fmaxf(ry, -q.w), q.w);
                const float dx = rx - cx, dy = ry - cy;
                const float d2 = fmaf(dx, dx, dy * dy);
                const float r  = __builtin_amdgcn_rsqf(d2);
                float s = fmaxf(fmaf(rih, r, -0.5f), 0.0f);
                s = (d2 > EPS) ? s : 0.0f;
                const float fx = s * dx, fy = s * dy;
                ax -= fx; ay -= fy;
                gx += fx; gy += fy;
                gx = __shfl(gx, src, 64);
                gy = __shfl(gy, src, 64);
            }
        } else {
            const float bx = me.x, by = me.y, hx = me.z, hy = me.w;
            #pragma unroll 4
            for (int m = 0; m < 64; ++m) {
                const float4 q = Jd[w][lane + m];
                const float dqx = q.x - bx, dqy = q.y - by;
                const float ovx = (hx + q.z) - fabsf(dqx);
                const float ovy = (hy + q.w) - fabsf(dqy);
                const bool hit = fminf(ovx, ovy) > 0.0f;
                const bool ux  = ovx <= ovy;
                const float fx = (hit && ux)  ? copysignf(0.5f * ovx, dqx) : 0.0f;
                const float fy = (hit && !ux) ? copysignf(0.5f * ovy, dqy) : 0.0f;
                ax -= fx; ay -= fy;
                gx += fx; gy += fy;
                gx = __shfl(gx, src, 64);
                gy = __shfl(gy, src, 64);
            }
        }
        atomicAdd(&out[(((J << 6) + lane) << 1)],     gx);
        atomicAdd(&out[(((J << 6) + lane) << 1) + 1], gy);
    } else {
        if (bodyC) {
            const float px = me.x, py = me.y, rih = me.z;
            #pragma unroll 7
            for (int k = 1; k < 64; ++k) {
                const float4 q = Jd[w][lane + k];
                const float dx = px - q.x, dy = py - q.y;
                const float d2 = fmaf(dx, dx, dy * dy);
                const float r  = __builtin_amdgcn_rsqf(d2);
                const float s  = fmaxf(fmaf(rih + q.z, r, -0.5f), 0.0f);
                ax = fmaf(s, dx, ax); ay = fmaf(s, dy, ay);
            }
        } else {
            const float bx = me.x, by = me.y, hx = me.z, hy = me.w;
            #pragma unroll 7
            for (int k = 1; k < 64; ++k) {
                const float4 q = Jd[w][lane + k];
                const float dax = bx - q.x, day = by - q.y;
                const float ovx = (hx + q.z) - fabsf(dax);
                const float ovy = (hy + q.w) - fabsf(day);
                const bool hit = fminf(ovx, ovy) > 0.0f;
                const bool ux  = ovx <= ovy;
                ax += (hit && ux)  ? copysignf(0.5f * ovx, dax) : 0.0f;
                ay += (hit && !ux) ? copysignf(0.5f * ovy, day) : 0.0f;
            }
        }
        ax += me.x; ay += me.y;
    }

    atomicAdd(&out[(i << 1)],     ax);
    atomicAdd(&out[(i << 1) + 1], ay);
}

extern "C" void kernel_launch(void* const* d_in, const int* in_sizes, int n_in,
                              void* d_out, int out_size, void* d_ws, size_t ws_size,
                              hipStream_t stream) {
    (void)n_in;

    const float2* cpos  = (const float2*)d_in[0];
    const float*  crad  = (const float*) d_in[1];
    const float2* apos  = (const float2*)d_in[2];
    const float2* ahalf = (const float2*)d_in[3];

    const int Nc = in_sizes[1];                 // 4096

    const int tile_pairs = (96 * 97) / 2;       // 4656
    const int blocks = tile_pairs / 4;          // 1164

    const size_t ws_need = (size_t)96 * 96 * 64 * sizeof(float2);   // 4.72 MB

    if (d_ws != nullptr && ws_size >= ws_need) {
        // atomic-free path: partials to private slots, then deterministic reduce
        float2* ws = (float2*)d_ws;
        collide_ws<<<blocks, 256, 0, stream>>>(cpos, crad, apos, ahalf, ws, Nc);
        reduce_ws<<<96, 64, 0, stream>>>(ws, (float2*)d_out);
    } else {
        // fallback: original atomic-scatter path
        hipMemsetAsync(d_out, 0, (size_t)out_size * sizeof(float), stream);
        collide_atomic<<<blocks, 256, 0, stream>>>(cpos, crad, apos, ahalf,
                                                   (float*)d_out, Nc);
    }
}